// Round 8
// baseline (2597.483 us; speedup 1.0000x reference)
//
#include <hip/hip_runtime.h>

#define SEQ 2048
#define D 128

typedef float v2f __attribute__((ext_vector_type(2)));
typedef float v4f __attribute__((ext_vector_type(4)));
#define LO2(v) __builtin_shufflevector(v, v, 0, 1)
#define HI2(v) __builtin_shufflevector(v, v, 2, 3)

// ---------------------------------------------------------------------------
// DPP helpers (R7/R10/R11-verified):
// ---------------------------------------------------------------------------
#define DPP_ADD(x, ctrl) \
    ((x) + __int_as_float(__builtin_amdgcn_update_dpp(0, __float_as_int(x), (ctrl), 0xf, 0xf, true)))
#define COMBINE8(x) do { x = DPP_ADD(x, 0xB1); x = DPP_ADD(x, 0x4E); x = DPP_ADD(x, 0x141); } while (0)
#define TAIL3(x)    do { x = DPP_ADD(x, 0x140); x = DPP_ADD(x, 0x142); x = DPP_ADD(x, 0x143); } while (0)
#define REDUCE16(x) do { x = DPP_ADD(x, 0xB1); x = DPP_ADD(x, 0x4E); x = DPP_ADD(x, 0x141); \
                         x = DPP_ADD(x, 0x140); } while (0)

// packed-fp32 rank-1 update; uses j0..j7, k0_..k7_, vcur from enclosing scope
#define UPDATE_J(MODE, WF, WI)                                                \
    if ((MODE) == 2) {                                                        \
        const v2f vc2 = {vcur, vcur};                                         \
        j0 = vc2 * k0_; j1 = vc2 * k1_; j2 = vc2 * k2_; j3 = vc2 * k3_;       \
        j4 = vc2 * k4_; j5 = vc2 * k5_; j6 = vc2 * k6_; j7 = vc2 * k7_;       \
    } else if ((MODE) == 1) {                                                 \
        const v2f wf2 = {(WF), (WF)};                                         \
        const float wvr_ = (WI) * vcur;                                       \
        const v2f wv2 = {wvr_, wvr_};                                         \
        j0 = __builtin_elementwise_fma(j0, wf2, wv2 * k0_);                   \
        j1 = __builtin_elementwise_fma(j1, wf2, wv2 * k1_);                   \
        j2 = __builtin_elementwise_fma(j2, wf2, wv2 * k2_);                   \
        j3 = __builtin_elementwise_fma(j3, wf2, wv2 * k3_);                   \
        j4 = __builtin_elementwise_fma(j4, wf2, wv2 * k4_);                   \
        j5 = __builtin_elementwise_fma(j5, wf2, wv2 * k5_);                   \
        j6 = __builtin_elementwise_fma(j6, wf2, wv2 * k6_);                   \
        j7 = __builtin_elementwise_fma(j7, wf2, wv2 * k7_);                   \
    }

// ---------------------------------------------------------------------------
// ROUND-23: fused producer/consumer, producer access pattern restored to the
// standalone layout that measured 43MB FETCH (R2 profile).
//  R22 postmortem: traffic (2.5GB) was NOT fences -- it's the producers' own
//  O(SEQ^2) prefix re-reads, which the standalone 2048x256-thread dispatch
//  absorbed in L2/L3 via lockstep cross-block prefix walks. The 8-serial-rows
//  blocks destroyed that temporal correlation. Fix:
//   * 512 producer blocks x 4 PARALLEL 256-thread groups, each group runs the
//     standalone per-row code verbatim (same i+=256 walk, same summation
//     order). All 512 co-resident (2 blocks/CU) -> lockstep restored.
//   * one fence + one flag per block (4 rows).
//   * consumer block 0 = byte-identical R15 scan, gating on 512 flags.
// ---------------------------------------------------------------------------
__global__ __launch_bounds__(1024, 2) void fused_kernel(
    const float* __restrict__ q, const float* __restrict__ k, const float* __restrict__ v,
    float* __restrict__ U, float* __restrict__ sl_arr,
    float* __restrict__ kqq_arr, float* __restrict__ vv_arr,
    float* __restrict__ kq_adj, float* __restrict__ vv_adj,
    float* __restrict__ kU_adj, double* __restrict__ invl_arr,
    float* __restrict__ out, int* flags)
{
    const int tid  = threadIdx.x;
    const int lane = tid & 63;

    // =======================================================================
    // PRODUCER blocks: 4 parallel 256-thread groups, group g -> row 4b+g
    // =======================================================================
    if (blockIdx.x != 0) {
        const int b = blockIdx.x - 1;     // 0..511
        const int g = tid >> 8;           // 0..3
        const int t = tid & 255;
        const int s = b * 4 + g;

        __shared__ float ks[4][D];
        __shared__ float vs[4][D];
        __shared__ float alpha[4][SEQ];
        __shared__ float red[4][8];
        __shared__ float upart[4][256];

        if (t < D) ks[g][t] = k[s * D + t];
        else vs[g][t - D] = v[s * D + (t - D)];
        __syncthreads();

        // pass 1: alpha_i = k_s.q_i, partials for kqq/sl, vv[s]  (i += 256)
        float p_a2 = 0.f, p_ab = 0.f;
        for (int i = t; i <= s; i += 256) {
            const float4* qr = (const float4*)(q + (size_t)i * D);
            const float4* vr = (const float4*)(v + (size_t)i * D);
            float a = 0.f, bb = 0.f;
#pragma unroll
            for (int j = 0; j < D / 4; ++j) {
                float4 q4 = qr[j];
                float4 v4 = vr[j];
                a += q4.x * ks[g][4 * j + 0] + q4.y * ks[g][4 * j + 1] + q4.z * ks[g][4 * j + 2] + q4.w * ks[g][4 * j + 3];
                bb += v4.x * vs[g][4 * j + 0] + v4.y * vs[g][4 * j + 1] + v4.z * vs[g][4 * j + 2] + v4.w * vs[g][4 * j + 3];
            }
            alpha[g][i] = a;
            p_a2 += a * a;
            p_ab += a * bb;
            if (i == s) vv_arr[s] = bb;  // v_s . v_s
        }
#pragma unroll
        for (int off = 1; off < 64; off <<= 1) {
            p_a2 += __shfl_xor(p_a2, off);
            p_ab += __shfl_xor(p_ab, off);
        }
        const int wid = t >> 6;   // 0..3 within group
        if ((t & 63) == 0) { red[g][wid] = p_a2; red[g][4 + wid] = p_ab; }
        __syncthreads();  // also makes alpha[] visible within group
        if (t == 0) {
            kqq_arr[s] = red[g][0] + red[g][1] + red[g][2] + red[g][3];
            sl_arr[s]  = red[g][4] + red[g][5] + red[g][6] + red[g][7];
            invl_arr[s] = 1.0 / (double)(s + 1);
        }

        // adjacency dots: first wave of group -> kq_adj[s+1], second -> vv_adj[s]
        if (t < 64) {
            if (s + 1 < SEQ) {
                float p2 = ks[g][t] * q[(size_t)(s + 1) * D + t]
                         + ks[g][t + 64] * q[(size_t)(s + 1) * D + 64 + t];
#pragma unroll
                for (int off = 1; off < 64; off <<= 1) p2 += __shfl_xor(p2, off);
                if (t == 0) kq_adj[s + 1] = p2;
            }
            if (s == 0 && t == 0) { kq_adj[0] = 0.f; kU_adj[0] = 0.f; vv_adj[0] = 0.f; }
        } else if (t < 128 && s > 0) {
            const int t2 = t - 64;
            float p2 = vs[g][t2] * v[(size_t)(s - 1) * D + t2]
                     + vs[g][t2 + 64] * v[(size_t)(s - 1) * D + 64 + t2];
#pragma unroll
            for (int off = 1; off < 64; off <<= 1) p2 += __shfl_xor(p2, off);
            if (t2 == 0) vv_adj[s] = p2;
        }

        // pass 2: U[s][c] = sum_i q[i][c]*alpha[i], parity-2 over h (R15 order)
        const int c = t & (D - 1);
        const int h = t >> 7;  // 0 or 1
        float a0 = 0.f, a1 = 0.f, a2 = 0.f, a3 = 0.f;
        int i = h;
        for (; i + 6 <= s; i += 8) {
            a0 = fmaf(q[(size_t)(i    ) * D + c], alpha[g][i    ], a0);
            a1 = fmaf(q[(size_t)(i + 2) * D + c], alpha[g][i + 2], a1);
            a2 = fmaf(q[(size_t)(i + 4) * D + c], alpha[g][i + 4], a2);
            a3 = fmaf(q[(size_t)(i + 6) * D + c], alpha[g][i + 6], a3);
        }
        for (; i <= s; i += 2) a0 = fmaf(q[(size_t)i * D + c], alpha[g][i], a0);
        upart[g][t] = (a0 + a1) + (a2 + a3);
        __syncthreads();

        // U store + kU_adj[s] = k_{s-1}.U_s
        float kup = 0.f;
        if (t < D) {
            const float uv = upart[g][t] + upart[g][t + D];
            U[(size_t)s * D + t] = uv;
            if (s > 0) kup = uv * k[(size_t)(s - 1) * D + t];
        }
#pragma unroll
        for (int off = 1; off < 64; off <<= 1) kup += __shfl_xor(kup, off);
        if (t == 0)  red[g][0] = kup;
        if (t == 64) red[g][1] = kup;
        __syncthreads();
        if (s > 0 && t == 0) kU_adj[s] = red[g][0] + red[g][1];

        // release all 4 rows with ONE device-scope fence + flag
        __syncthreads();
        __threadfence();
        if (tid == 0)
            __hip_atomic_store(&flags[b], 1, __ATOMIC_RELEASE, __HIP_MEMORY_SCOPE_AGENT);
        return;
    }

    // =======================================================================
    // CONSUMER block 0: R15 scan + block-flag gates (512 flags, 4 rows each)
    // =======================================================================
#define WAITGATE(T)                                                           \
    {                                                                         \
        int t_ = (T); if (t_ > SEQ - 1) t_ = SEQ - 1;                         \
        const int fb_ = t_ >> 2;   /* need flags[0..fb_] */                   \
        for (;;) {                                                            \
            int ok_ = 1;                                                      \
            _Pragma("unroll")                                                 \
            for (int jj_ = 0; jj_ < 8; ++jj_) {                               \
                const int fi_ = lane + 64 * jj_;                              \
                if (fi_ <= fb_)                                               \
                    ok_ &= __hip_atomic_load(&flags[fi_],                     \
                             __ATOMIC_ACQUIRE, __HIP_MEMORY_SCOPE_AGENT);     \
            }                                                                 \
            if (__all(ok_)) break;                                            \
            __builtin_amdgcn_s_sleep(8);                                      \
        }                                                                     \
    }

    const int w    = __builtin_amdgcn_readfirstlane(tid >> 6);  // 0..15
    const int r    = tid >> 3;        // my row 0..127
    const int cg   = tid & 7;
    const int c0s  = cg * 20;         // swizzled LDS chunk offset

    v2f j0 = {0.f, 0.f}, j1 = j0, j2 = j0, j3 = j0, j4 = j0, j5 = j0, j6 = j0, j7 = j0;

    __shared__ float ring[3][3][160];                 // [phase][q,u,k][swizzled]
    __shared__ __align__(16) float wred[3][16][4];    // [phase][wave][r1,r2,r3,r4]
    __shared__ __align__(16) float decLDS[3][4];      // [phase][wf,wi,mode,-]

    // stagers: waves 6..11 (tid 384..767) — wave0 stays staging-free
    const bool stager = (tid >= 384) && (tid < 768);
    const int  which  = (tid >> 7) - 3;    // 0:q 1:u 2:k (when stager)
    const int  sidx   = tid & 127;
    const int  widx   = ((sidx >> 4) * 20) + (sidx & 15);  // swizzled write idx

    // rows 0..99 ready before touching any produced data
    WAITGATE(99)

    // ---- prologue: stage phases 0,1; gstage holds phase-2 data ----
    // invariant: phase j holds q_{j+1}, u_{j+1}, k_j
    float gstage = 0.f;
    if (stager) {
        if (which == 0) {
            ring[0][0][widx] = q[(size_t)1 * D + sidx];
            ring[1][0][widx] = q[(size_t)2 * D + sidx];
            gstage = q[(size_t)3 * D + sidx];
        } else if (which == 1) {
            ring[0][1][widx] = U[(size_t)1 * D + sidx];
            ring[1][1][widx] = U[(size_t)2 * D + sidx];
            gstage = U[(size_t)3 * D + sidx];
        } else {
            ring[0][2][widx] = k[sidx];
            ring[1][2][widx] = k[(size_t)1 * D + sidx];
            gstage = k[(size_t)2 * D + sidx];
        }
    }
    float vcur = v[r], vnext = v[(size_t)D + r], vn2 = v[(size_t)2 * D + r];

    // dec_0 is always mode 2 (first step: J_0 = v_0 k_0^T); read at body 0
    float dwf = 0.f, dwi = 1.f;
    int dmode = 2;
    if (tid == 0) { decLDS[0][0] = 0.f; decLDS[0][1] = 1.f; decLDS[0][2] = 2.f; decLDS[0][3] = 0.f; }

    double SJ = 0.0, AJJ = 0.0, trSvv = 0.0;  // live on wave 0 only
    if (w == 0) {
        const double sl0 = (double)sl_arr[0];
        const double kq0 = (double)kqq_arr[0];
        const double vv0 = (double)vv_arr[0];
        trSvv = vv0;
        SJ  = sl0;
        AJJ = vv0 * kq0;
        if (lane == 0) {
            out[0] = (float)((0.5 * trSvv - SJ + 0.5 * AJJ) * invl_arr[0]);
            out[SEQ] = 1.f;
        }
    }
    __syncthreads();

#define STEP_BODY(I, P, PN, PW)                                               \
{                                                                             \
    float c_sl = 0.f, c_kq = 0.f, c_vv = 0.f, c_kqa = 0.f, c_vva = 0.f,       \
          c_vvp = 0.f, c_kua = 0.f;                                           \
    double c_inv = 0.0;                                                       \
    if (w == 0) {                                                             \
        c_sl  = sl_arr[(I) + 1];  c_kq  = kqq_arr[(I) + 1];                   \
        c_vv  = vv_arr[(I) + 1];  c_kqa = kq_adj[(I) + 1];                    \
        c_vva = vv_adj[(I) + 1];  c_vvp = vv_arr[(I)];                        \
        c_kua = kU_adj[(I) + 1];  c_inv = invl_arr[(I) + 1];                  \
    }                                                                         \
    const v4f Qa = ((const v4f*)&ring[P][0][c0s])[0];                         \
    const v4f Qb = ((const v4f*)&ring[P][0][c0s])[1];                         \
    const v4f Qc = ((const v4f*)&ring[P][0][c0s])[2];                         \
    const v4f Qd = ((const v4f*)&ring[P][0][c0s])[3];                         \
    const v4f Ua = ((const v4f*)&ring[P][1][c0s])[0];                         \
    const v4f Ub = ((const v4f*)&ring[P][1][c0s])[1];                         \
    const v4f Uc = ((const v4f*)&ring[P][1][c0s])[2];                         \
    const v4f Ud = ((const v4f*)&ring[P][1][c0s])[3];                         \
    const v4f Ka = ((const v4f*)&ring[P][2][c0s])[0];                         \
    const v4f Kb = ((const v4f*)&ring[P][2][c0s])[1];                         \
    const v4f Kc = ((const v4f*)&ring[P][2][c0s])[2];                         \
    const v4f Kd = ((const v4f*)&ring[P][2][c0s])[3];                         \
    const v2f k0_ = LO2(Ka), k1_ = HI2(Ka), k2_ = LO2(Kb), k3_ = HI2(Kb);     \
    const v2f k4_ = LO2(Kc), k5_ = HI2(Kc), k6_ = LO2(Kd), k7_ = HI2(Kd);     \
    v2f aq0 = {0.f, 0.f}, aq1 = aq0, aq2 = aq0, aq3 = aq0;                    \
    aq0 = __builtin_elementwise_fma(j0, LO2(Qa), aq0);                        \
    aq1 = __builtin_elementwise_fma(j1, HI2(Qa), aq1);                        \
    aq2 = __builtin_elementwise_fma(j2, LO2(Qb), aq2);                        \
    aq3 = __builtin_elementwise_fma(j3, HI2(Qb), aq3);                        \
    aq0 = __builtin_elementwise_fma(j4, LO2(Qc), aq0);                        \
    aq1 = __builtin_elementwise_fma(j5, HI2(Qc), aq1);                        \
    aq2 = __builtin_elementwise_fma(j6, LO2(Qd), aq2);                        \
    aq3 = __builtin_elementwise_fma(j7, HI2(Qd), aq3);                        \
    const v2f sq_ = (aq0 + aq1) + (aq2 + aq3);                                \
    float Yq = sq_.x + sq_.y;                                                 \
    v2f au0 = {0.f, 0.f}, au1 = au0, au2 = au0, au3 = au0;                    \
    au0 = __builtin_elementwise_fma(j0, LO2(Ua), au0);                        \
    au1 = __builtin_elementwise_fma(j1, HI2(Ua), au1);                        \
    au2 = __builtin_elementwise_fma(j2, LO2(Ub), au2);                        \
    au3 = __builtin_elementwise_fma(j3, HI2(Ub), au3);                        \
    au0 = __builtin_elementwise_fma(j4, LO2(Uc), au0);                        \
    au1 = __builtin_elementwise_fma(j5, HI2(Uc), au1);                        \
    au2 = __builtin_elementwise_fma(j6, LO2(Ud), au2);                        \
    au3 = __builtin_elementwise_fma(j7, HI2(Ud), au3);                        \
    const v2f su_ = (au0 + au1) + (au2 + au3);                                \
    float Yw = su_.x + su_.y;                                                 \
    COMBINE8(Yq);                                                             \
    COMBINE8(Yw);                                                             \
    float z1 = vnext * Yq;                                                    \
    float z2 = Yq * Yq;                                                       \
    float z3 = vcur  * Yq;                                                    \
    float z4 = vnext * Yw;                                                    \
    TAIL3(z1);                                                                \
    TAIL3(z2);                                                                \
    TAIL3(z3);                                                                \
    TAIL3(z4);                                                                \
    if (lane == 63) *(float4*)&wred[P][w][0] = make_float4(z1, z2, z3, z4);   \
    __syncthreads();                                                          \
    if (stager) {                                                             \
        ring[PW][which][widx] = gstage;                                       \
        const int tq_ = ((I) + 4 < SEQ) ? (I) + 4 : SEQ - 1;                  \
        const int tk_ = ((I) + 3 < SEQ) ? (I) + 3 : SEQ - 1;                  \
        gstage = (which == 0) ? q[(size_t)tq_ * D + sidx]                     \
               : (which == 1) ? U[(size_t)tq_ * D + sidx]                     \
                              : k[(size_t)tk_ * D + sidx];                    \
    }                                                                         \
    const int tv_ = ((I) + 3 < SEQ) ? (I) + 3 : SEQ - 1;                      \
    const float vnew_ = v[(size_t)tv_ * D + r];                               \
    if (w == 0) {                                                             \
        float4 ww = *(const float4*)&wred[P][lane & 15][0];                   \
        const float odwf = dwf, odwi = dwi;                                   \
        const int   odmode = dmode;                                           \
        UPDATE_J(odmode, odwf, odwi)                                          \
        REDUCE16(ww.x);                                                       \
        REDUCE16(ww.y);                                                       \
        REDUCE16(ww.z);                                                       \
        REDUCE16(ww.w);                                                       \
        double a_, b_;                                                        \
        if (odmode == 2)      { a_ = 0.0; b_ = 1.0; }                         \
        else if (odmode == 1) { a_ = (double)odwf; b_ = (double)odwi; }       \
        else                  { a_ = 1.0; b_ = 0.0; }                         \
        const double kqa = (double)c_kqa, vva = (double)c_vva;                \
        const double vvp = (double)c_vvp, kua = (double)c_kua;                \
        const double r1 = (double)ww.x * 0.125, r2 = (double)ww.y * 0.125;    \
        const double r3 = (double)ww.z * 0.125, r4 = (double)ww.w * 0.125;    \
        const double Jqv  = a_ * r1 + b_ * (kqa * vva);                       \
        const double Jq2  = a_ * a_ * r2 + 2.0 * a_ * b_ * kqa * r3          \
                          + b_ * b_ * kqa * kqa * vvp;                        \
        const double AJl_ = a_ * r4 + b_ * kua * vva;                         \
        trSvv += (double)c_vv;                                                \
        SJ    += Jqv;                                                         \
        AJJ   += Jq2;                                                         \
        const double s_l  = (double)c_sl;                                     \
        const double A_ll = (double)c_vv * (double)c_kq;                      \
        const double AJJ_s  = (AJJ == 0.0)  ? 1.0 : AJJ;                      \
        const double A_ll_s = (A_ll == 0.0) ? 1.0 : A_ll;                     \
        const double denom   = AJJ * A_ll - AJl_ * AJl_;                      \
        const double denom_s = (denom == 0.0) ? 1.0 : denom;                  \
        const double rden = 1.0 / denom_s;                                    \
        const double wf = (A_ll * SJ - AJl_ * s_l) * rden;                    \
        const double wi = (AJJ * s_l - AJl_ * SJ) * rden;                     \
        double wf_c, wi_c;                                                    \
        if (wi <= 0.0)      { wf_c = SJ / AJJ_s;  wi_c = 0.0; }               \
        else if (wf <= 0.0) { wf_c = 0.0;         wi_c = s_l / A_ll_s; }      \
        else                { wf_c = wf;          wi_c = wi; }                \
        const bool do_update = (s_l * AJJ_s - AJl_ * SJ) > 0.0;               \
        int mode;                                                             \
        if (do_update) {                                                      \
            mode = 1;                                                         \
            const double nSJ = wf_c * SJ + wi_c * s_l;                        \
            AJJ = wf_c * wf_c * AJJ + 2.0 * wf_c * wi_c * AJl_                \
                + wi_c * wi_c * A_ll;                                         \
            SJ = nSJ;                                                         \
        } else {                                                              \
            mode = 0;                                                         \
        }                                                                     \
        dwf = (float)wf_c; dwi = (float)wi_c; dmode = mode;                   \
        if (lane == 0) {                                                      \
            out[(I) + 1] = (float)((0.5 * trSvv - SJ + 0.5 * AJJ) * c_inv);   \
            out[SEQ + (I) + 1] = mode ? 1.f : 0.f;                            \
            *(float4*)&decLDS[PN][0] = make_float4(dwf, dwi, (float)mode, 0.f);\
        }                                                                     \
    } else {                                                                  \
        const float4 df = *(const float4*)&decLDS[P][0];                      \
        dwf = df.x; dwi = df.y; dmode = (int)df.z;                            \
        UPDATE_J(dmode, dwf, dwi)                                             \
    }                                                                         \
    vcur = vnext; vnext = vn2; vn2 = vnew_;                                   \
}

    // bodies I = 0..SEQ-2 (2047 of them): 682 x3-unrolled + 1 tail (2046%3==0)
    for (int i = 0; i + 2 < SEQ - 1; i += 3) {
        if (i && (i % 96) == 0) WAITGATE(i + 99)
        STEP_BODY(i,     0, 1, 2)
        STEP_BODY(i + 1, 1, 2, 0)
        STEP_BODY(i + 2, 2, 0, 1)
    }
    STEP_BODY(SEQ - 2, 0, 1, 2)
#undef STEP_BODY
#undef WAITGATE

    // ---- epilogue: apply final update (dec_{SEQ-1}, phase (SEQ-1)%3 = 1) ----
    __syncthreads();  // make wave0's decLDS[1] write visible
    {
        const float4 df = *(const float4*)&decLDS[1][0];
        const float fwf = df.x, fwi = df.y;
        const int   fmode = (int)df.z;
        const v4f Ka = ((const v4f*)&ring[1][2][c0s])[0];
        const v4f Kb = ((const v4f*)&ring[1][2][c0s])[1];
        const v4f Kc = ((const v4f*)&ring[1][2][c0s])[2];
        const v4f Kd = ((const v4f*)&ring[1][2][c0s])[3];
        const v2f k0_ = LO2(Ka), k1_ = HI2(Ka), k2_ = LO2(Kb), k3_ = HI2(Kb);
        const v2f k4_ = LO2(Kc), k5_ = HI2(Kc), k6_ = LO2(Kd), k7_ = HI2(Kd);
        UPDATE_J(fmode, fwf, fwi)
        float* jbase = out + 2 * SEQ + (size_t)r * D + cg * 16;
        *(v4f*)(jbase + 0)  = __builtin_shufflevector(j0, j1, 0, 1, 2, 3);
        *(v4f*)(jbase + 4)  = __builtin_shufflevector(j2, j3, 0, 1, 2, 3);
        *(v4f*)(jbase + 8)  = __builtin_shufflevector(j4, j5, 0, 1, 2, 3);
        *(v4f*)(jbase + 12) = __builtin_shufflevector(j6, j7, 0, 1, 2, 3);
    }
}

extern "C" void kernel_launch(void* const* d_in, const int* in_sizes, int n_in,
                              void* d_out, int out_size, void* d_ws, size_t ws_size,
                              hipStream_t stream) {
    (void)in_sizes; (void)n_in; (void)out_size; (void)ws_size;
    const float* q = (const float*)d_in[0];
    const float* k = (const float*)d_in[1];
    const float* v = (const float*)d_in[2];
    float* out = (float*)d_out;

    float* U      = (float*)d_ws;            // SEQ*D floats (1 MB)
    float* sl     = U + (size_t)SEQ * D;     // SEQ
    float* kqq    = sl + SEQ;                // SEQ
    float* vv     = kqq + SEQ;               // SEQ
    float* kq_adj = vv + SEQ;                // SEQ
    float* vv_adj = kq_adj + SEQ;            // SEQ
    float* kU_adj = vv_adj + SEQ;            // SEQ
    double* invl  = (double*)(kU_adj + SEQ); // SEQ doubles (8B-aligned)
    int*    flags = (int*)(invl + SEQ);      // 512 ints (block-ready flags)

    hipMemsetAsync(flags, 0, 512 * sizeof(int), stream);
    fused_kernel<<<513, 1024, 0, stream>>>(q, k, v, U, sl, kqq, vv,
                                           kq_adj, vv_adj, kU_adj, invl,
                                           out, flags);
}